// Round 4
// baseline (1278.478 us; speedup 1.0000x reference)
//
#include <hip/hip_runtime.h>
#include <cstdint>

// ---------- constants ----------
#define BB 2
#define LL 2048
#define DD 1024
#define HH 16
#define DH 64
#define BH 32          // B*H
#define MPROJ 12288    // 3*B*L
#define MOUT 4096      // B*L

typedef __attribute__((ext_vector_type(8))) short bhalf8;   // 8 bf16
typedef __attribute__((ext_vector_type(4))) float f32x4;

__device__ __forceinline__ unsigned short f2bf(float f) {
  union { float f; unsigned u; } c; c.f = f;
  unsigned u = c.u;
  u = (u + 0x7fffu + ((u >> 16) & 1u)) >> 16;
  return (unsigned short)u;
}

// ---------- workspace layout (bytes) ----------
constexpr size_t OFF_XBF    = 0;                                  // 12288*1024 bf16
constexpr size_t OFF_WQBF   = OFF_XBF    + (size_t)MPROJ*DD*2;
constexpr size_t OFF_WOBF   = OFF_WQBF   + (size_t)DD*DD*2;
constexpr size_t OFF_QBF    = OFF_WOBF   + (size_t)DD*DD*2;       // [bh][l][d]
constexpr size_t OFF_KBF    = OFF_QBF    + (size_t)BH*LL*DH*2;
constexpr size_t OFF_VTBF   = OFF_KBF    + (size_t)BH*LL*DH*2;    // [bh][d][l]
constexpr size_t OFF_ATTNBF = OFF_VTBF   + (size_t)BH*LL*DH*2;    // [b*L+l][D]
constexpr size_t OFF_WAS    = OFF_ATTNBF + (size_t)MOUT*DD*2;     // [2][16][1024] f32
constexpr size_t OFF_BAS    = OFF_WAS    + (size_t)2*HH*DD*4;
constexpr size_t OFF_AARR   = OFF_BAS    + 256;                   // [bh][l] f32
constexpr size_t OFF_SARR   = OFF_AARR   + (size_t)BH*LL*4;
constexpr size_t OFF_MARR   = OFF_SARR   + (size_t)BH*LL*4;
constexpr size_t OFF_ZARR   = OFF_MARR   + (size_t)BH*LL*4;
constexpr size_t WS_NEED    = OFF_ZARR   + (size_t)BH*LL*4;

// ---------- cast fp32 -> bf16 (vectorized) ----------
__global__ __launch_bounds__(256) void cast_f32_bf16(
    const float* __restrict__ src, unsigned short* __restrict__ dst, int n4) {
  int i = blockIdx.x * 256 + threadIdx.x;
  if (i < n4) {
    float4 v = ((const float4*)src)[i];
    ushort4 o;
    o.x = f2bf(v.x); o.y = f2bf(v.y); o.z = f2bf(v.z); o.w = f2bf(v.w);
    ((ushort4*)dst)[i] = o;
  }
}

// ---------- wA/wS vectors from Wq (f64 accum) ----------
__global__ __launch_bounds__(256) void prep_rel(
    const float* __restrict__ Wq, const float* __restrict__ bq,
    const float* __restrict__ rel, float* __restrict__ wAS, float* __restrict__ bAS) {
  int idx = blockIdx.x * 256 + threadIdx.x;
  if (idx >= 2 * HH * DD) return;
  int kind = idx >> 14;
  int h = (idx >> 10) & 15;
  int c = idx & 1023;
  double s = 0.0;
  for (int d = 0; d < DH; ++d) {
    double coef = kind ? 1.0 : (double)rel[d];   // rel_emb row 0
    s += coef * (double)Wq[(size_t)(h * DH + d) * DD + c];
  }
  wAS[idx] = (float)s;
  if (c == 0) {
    double b = 0.0;
    for (int d = 0; d < DH; ++d) {
      double coef = kind ? 1.0 : (double)rel[d];
      b += coef * (double)bq[h * DH + d];
    }
    bAS[kind * HH + h] = (float)b;
  }
}

// ---------- A_arr/S_arr = query @ wAS^T + bAS (f64 accum) ----------
__global__ __launch_bounds__(256) void rel_AS(
    const float* __restrict__ query, const float* __restrict__ wAS,
    const float* __restrict__ bAS, float* __restrict__ A_arr, float* __restrict__ S_arr) {
  int r = blockIdx.x * 8 + (threadIdx.x >> 5);  // global row in [0,4096)
  int j = threadIdx.x & 31;                      // kind*16 + h
  const float* qrow = query + (size_t)r * DD;
  const float* w = wAS + (size_t)j * DD;
  double s = 0.0;
  for (int k = 0; k < DD; k += 4) {
    float4 qv = *(const float4*)(qrow + k);
    float4 wv = *(const float4*)(w + k);
    s += (double)qv.x * wv.x + (double)qv.y * wv.y +
         (double)qv.z * wv.z + (double)qv.w * wv.w;
  }
  s += (double)bAS[j];
  int b = r >> 11, l = r & 2047;
  int h = j & 15;
  size_t idx = (size_t)(b * HH + h) * LL + l;
  if (j >> 4) S_arr[idx] = (float)s; else A_arr[idx] = (float)s;
}

// ---------- bf16 MFMA GEMM, C = A @ B^T + bias ----------
template <int EPI>
__global__ __launch_bounds__(256) void gemm_bt(
    const unsigned short* __restrict__ A, const unsigned short* __restrict__ Bm,
    const float* __restrict__ bias,
    unsigned short* __restrict__ q_bf, unsigned short* __restrict__ k_bf,
    unsigned short* __restrict__ vt_bf, float* __restrict__ outp) {
  __shared__ unsigned short lA[2][128 * 32];
  __shared__ unsigned short lB[2][128 * 32];
  const int bi = blockIdx.x, bj = blockIdx.y;
  const int t = threadIdx.x;
  const int w = t >> 6, lane = t & 63;
  const int lr = lane & 15, kg = lane >> 4;
  const int wr = w >> 1, wc = w & 1;

  const int srow = t >> 1, scol = (t & 1) * 16;
  const unsigned short* gA = A + (size_t)(bi * 128 + srow) * DD + scol;
  const unsigned short* gB = Bm + (size_t)(bj * 128 + srow) * DD + scol;
  const int soff = srow * 32 + scol;

  const f32x4 Z4 = {0.f, 0.f, 0.f, 0.f};
  f32x4 acc[4][4];
#pragma unroll
  for (int m = 0; m < 4; ++m)
#pragma unroll
    for (int n = 0; n < 4; ++n) acc[m][n] = Z4;

  {
    uint4 ra0 = *(const uint4*)(gA);
    uint4 ra1 = *(const uint4*)(gA + 8);
    uint4 rb0 = *(const uint4*)(gB);
    uint4 rb1 = *(const uint4*)(gB + 8);
    *(uint4*)&lA[0][soff] = ra0; *(uint4*)&lA[0][soff + 8] = ra1;
    *(uint4*)&lB[0][soff] = rb0; *(uint4*)&lB[0][soff + 8] = rb1;
  }
  __syncthreads();

  int cur = 0;
  for (int kt = 0; kt < 32; ++kt) {
    uint4 ra0, ra1, rb0, rb1;
    const bool more = (kt + 1 < 32);
    if (more) {
      const int k0 = (kt + 1) * 32;
      ra0 = *(const uint4*)(gA + k0);
      ra1 = *(const uint4*)(gA + k0 + 8);
      rb0 = *(const uint4*)(gB + k0);
      rb1 = *(const uint4*)(gB + k0 + 8);
    }
    bhalf8 af[4], bf[4];
#pragma unroll
    for (int m = 0; m < 4; ++m)
      af[m] = *(const bhalf8*)&lA[cur][(wr * 64 + m * 16 + lr) * 32 + kg * 8];
#pragma unroll
    for (int n = 0; n < 4; ++n)
      bf[n] = *(const bhalf8*)&lB[cur][(wc * 64 + n * 16 + lr) * 32 + kg * 8];
#pragma unroll
    for (int m = 0; m < 4; ++m)
#pragma unroll
      for (int n = 0; n < 4; ++n)
        acc[m][n] = __builtin_amdgcn_mfma_f32_16x16x32_bf16(af[m], bf[n], acc[m][n], 0, 0, 0);
    if (more) {
      *(uint4*)&lA[cur ^ 1][soff] = ra0; *(uint4*)&lA[cur ^ 1][soff + 8] = ra1;
      *(uint4*)&lB[cur ^ 1][soff] = rb0; *(uint4*)&lB[cur ^ 1][soff + 8] = rb1;
    }
    __syncthreads();
    cur ^= 1;
  }

  // epilogue
#pragma unroll
  for (int n = 0; n < 4; ++n) {
    const int gcol = bj * 128 + wc * 64 + n * 16 + lr;
    const float bv = bias[gcol];
#pragma unroll
    for (int m = 0; m < 4; ++m) {
#pragma unroll
      for (int r = 0; r < 4; ++r) {
        const int grow = bi * 128 + wr * 64 + m * 16 + kg * 4 + r;
        float v = acc[m][n][r] + bv;
        if (EPI == 0) {
          const int src = grow >> 12;
          const int rl = grow & 4095;
          const int b = rl >> 11, l2 = rl & 2047;
          const int h = gcol >> 6, d = gcol & 63;
          const int bh = b * HH + h;
          unsigned short bfv = f2bf(v);
          if (src == 0)      q_bf[((size_t)bh * LL + l2) * DH + d] = bfv;
          else if (src == 1) k_bf[((size_t)bh * LL + l2) * DH + d] = bfv;
          else               vt_bf[((size_t)bh * DH + d) * LL + l2] = bfv;
        } else {
          outp[(size_t)grow * DD + gcol] = v;
        }
      }
    }
  }
}

// K-tile LDS swizzle: elem' = elem ^ ((row&7)*8)  (byte ^= (row&7)<<4)
// breaks the 16-way bank conflict of 128B rows read as ds_read_b128.

// ---------- attention phase A: per-row max and 1/sum ----------
__global__ __launch_bounds__(256) void attn_a(
    const unsigned short* __restrict__ q_bf, const unsigned short* __restrict__ k_bf,
    const float* __restrict__ A_arr, const float* __restrict__ S_arr,
    float* __restrict__ M_arr, float* __restrict__ Zinv_arr) {
  __shared__ unsigned short lK[64 * 64];
  const int bid = blockIdx.x;
  const int bh = bid >> 5, qt = bid & 31;
  const int t = threadIdx.x, w = t >> 6, lane = t & 63;
  const int lr = lane & 15, kg = lane >> 4;
  const int qrow0 = qt * 64 + w * 16;

  const unsigned short* qbase = q_bf + ((size_t)bh * LL + qrow0 + lr) * DH + kg * 8;
  bhalf8 aq0 = *(const bhalf8*)qbase;
  bhalf8 aq1 = *(const bhalf8*)(qbase + 32);

  float Av[4], Sv[4], Mr[4], ps[4];
  int myrow[4];
#pragma unroll
  for (int r = 0; r < 4; ++r) {
    myrow[r] = qrow0 + kg * 4 + r;
    Av[r] = A_arr[(size_t)bh * LL + myrow[r]];
    Sv[r] = S_arr[(size_t)bh * LL + myrow[r]];
    Mr[r] = -INFINITY; ps[r] = 0.f;
  }

  const int srow = t >> 2, scol = (t & 3) * 16;
  const int se0 = srow * 64 + ((((t & 3) * 2 + 0) ^ (srow & 7)) * 8);
  const int se1 = srow * 64 + ((((t & 3) * 2 + 1) ^ (srow & 7)) * 8);
  const unsigned short* kbase = k_bf + (size_t)bh * LL * DH;
  const f32x4 Z4 = {0.f, 0.f, 0.f, 0.f};

  for (int kt = 0; kt <= qt; ++kt) {
    __syncthreads();
    {
      const unsigned short* src = kbase + (size_t)(kt * 64 + srow) * DH + scol;
      uint4 v0 = *(const uint4*)src;
      uint4 v1 = *(const uint4*)(src + 8);
      *(uint4*)&lK[se0] = v0;
      *(uint4*)&lK[se1] = v1;
    }
    __syncthreads();
    f32x4 acc[4];
#pragma unroll
    for (int n = 0; n < 4; ++n) {
      acc[n] = Z4;
      const int rowb = n * 16 + lr;
      bhalf8 b0 = *(const bhalf8*)&lK[rowb * 64 + ((kg ^ (rowb & 7)) * 8)];
      bhalf8 b1 = *(const bhalf8*)&lK[rowb * 64 + (((4 + kg) ^ (rowb & 7)) * 8)];
      acc[n] = __builtin_amdgcn_mfma_f32_16x16x32_bf16(aq0, b0, acc[n], 0, 0, 0);
      acc[n] = __builtin_amdgcn_mfma_f32_16x16x32_bf16(aq1, b1, acc[n], 0, 0, 0);
    }
    float lg[4][4];
#pragma unroll
    for (int n = 0; n < 4; ++n) {
      const int gcol = kt * 64 + n * 16 + lr;
#pragma unroll
      for (int r = 0; r < 4; ++r) {
        float rel = Av[r] - (float)(2047 - myrow[r] + gcol) * Sv[r];
        float l = (acc[n][r] + rel) * 0.125f;
        lg[n][r] = (gcol <= myrow[r]) ? l : -1e30f;
      }
    }
#pragma unroll
    for (int r = 0; r < 4; ++r) {
      float tmax = fmaxf(fmaxf(lg[0][r], lg[1][r]), fmaxf(lg[2][r], lg[3][r]));
      tmax = fmaxf(tmax, __shfl_xor(tmax, 1));
      tmax = fmaxf(tmax, __shfl_xor(tmax, 2));
      tmax = fmaxf(tmax, __shfl_xor(tmax, 4));
      tmax = fmaxf(tmax, __shfl_xor(tmax, 8));
      float Mn = fmaxf(Mr[r], tmax);
      float s = ps[r] * __expf(Mr[r] - Mn);
      s += __expf(lg[0][r] - Mn) + __expf(lg[1][r] - Mn) +
           __expf(lg[2][r] - Mn) + __expf(lg[3][r] - Mn);
      ps[r] = s; Mr[r] = Mn;
    }
  }
#pragma unroll
  for (int r = 0; r < 4; ++r) {
    float s = ps[r];
    s += __shfl_xor(s, 1); s += __shfl_xor(s, 2);
    s += __shfl_xor(s, 4); s += __shfl_xor(s, 8);
    if (lr == 0) {
      M_arr[(size_t)bh * LL + myrow[r]] = Mr[r];
      Zinv_arr[(size_t)bh * LL + myrow[r]] = 1.0f / s;
    }
  }
}

// ---------- attention phase B: weights write + PV ----------
__global__ __launch_bounds__(256) void attn_b(
    const unsigned short* __restrict__ q_bf, const unsigned short* __restrict__ k_bf,
    const unsigned short* __restrict__ vt_bf,
    const float* __restrict__ A_arr, const float* __restrict__ S_arr,
    const float* __restrict__ M_arr, const float* __restrict__ Zinv_arr,
    float* __restrict__ w_out, unsigned short* __restrict__ attn_bf) {
  __shared__ unsigned short lK[64 * 64];
  __shared__ unsigned short lW[64][72];   // bf16 weights for PV (+8 pad)
  __shared__ float lWf32[64][68];         // f32 weights staging (+4 pad)
  const int bid = blockIdx.x;
  const int bh = bid >> 5, qt = bid & 31;
  const int t = threadIdx.x, w = t >> 6, lane = t & 63;
  const int lr = lane & 15, kg = lane >> 4;
  const int qrow0 = qt * 64 + w * 16;

  const unsigned short* qbase = q_bf + ((size_t)bh * LL + qrow0 + lr) * DH + kg * 8;
  bhalf8 aq0 = *(const bhalf8*)qbase;
  bhalf8 aq1 = *(const bhalf8*)(qbase + 32);

  float Av[4], Sv[4], Mv[4], Zv[4];
  int myrow[4];
#pragma unroll
  for (int r = 0; r < 4; ++r) {
    myrow[r] = qrow0 + kg * 4 + r;
    Av[r] = A_arr[(size_t)bh * LL + myrow[r]];
    Sv[r] = S_arr[(size_t)bh * LL + myrow[r]];
    Mv[r] = M_arr[(size_t)bh * LL + myrow[r]];
    Zv[r] = Zinv_arr[(size_t)bh * LL + myrow[r]];
  }

  const f32x4 Z4 = {0.f, 0.f, 0.f, 0.f};
  f32x4 oacc[4];
#pragma unroll
  for (int n = 0; n < 4; ++n) oacc[n] = Z4;

  const int srow = t >> 2, scol = (t & 3) * 16;
  const int se0 = srow * 64 + ((((t & 3) * 2 + 0) ^ (srow & 7)) * 8);
  const int se1 = srow * 64 + ((((t & 3) * 2 + 1) ^ (srow & 7)) * 8);
  const unsigned short* kbase = k_bf + (size_t)bh * LL * DH;
  const unsigned short* vtb = vt_bf + (size_t)bh * DH * LL;

  // masked tiles: barrier-free coalesced zero fill
  const int drow = t >> 2, dcol = (t & 3) * 16;
  for (int kt = qt + 1; kt < 32; ++kt) {
    float* dst = w_out + ((size_t)bh * LL + qt * 64 + drow) * LL + kt * 64 + dcol;
    float4 z = make_float4(0.f, 0.f, 0.f, 0.f);
    *(float4*)(dst) = z; *(float4*)(dst + 4) = z;
    *(float4*)(dst + 8) = z; *(float4*)(dst + 12) = z;
  }

  for (int kt = 0; kt <= qt; ++kt) {
    __syncthreads();
    {
      const unsigned short* src = kbase + (size_t)(kt * 64 + srow) * DH + scol;
      uint4 v0 = *(const uint4*)src;
      uint4 v1 = *(const uint4*)(src + 8);
      *(uint4*)&lK[se0] = v0;
      *(uint4*)&lK[se1] = v1;
    }
    __syncthreads();
    f32x4 acc[4];
#pragma unroll
    for (int n = 0; n < 4; ++n) {
      acc[n] = Z4;
      const int rowb = n * 16 + lr;
      bhalf8 b0 = *(const bhalf8*)&lK[rowb * 64 + ((kg ^ (rowb & 7)) * 8)];
      bhalf8 b1 = *(const bhalf8*)&lK[rowb * 64 + (((4 + kg) ^ (rowb & 7)) * 8)];
      acc[n] = __builtin_amdgcn_mfma_f32_16x16x32_bf16(aq0, b0, acc[n], 0, 0, 0);
      acc[n] = __builtin_amdgcn_mfma_f32_16x16x32_bf16(aq1, b1, acc[n], 0, 0, 0);
    }
#pragma unroll
    for (int n = 0; n < 4; ++n) {
      const int gcol = kt * 64 + n * 16 + lr;
#pragma unroll
      for (int r = 0; r < 4; ++r) {
        float rel = Av[r] - (float)(2047 - myrow[r] + gcol) * Sv[r];
        float l = (acc[n][r] + rel) * 0.125f;
        float wgt = (gcol <= myrow[r]) ? __expf(l - Mv[r]) * Zv[r] : 0.f;
        lW[w * 16 + kg * 4 + r][n * 16 + lr] = f2bf(wgt);
        lWf32[w * 16 + kg * 4 + r][n * 16 + lr] = wgt;
      }
    }
    __syncthreads();
    // coalesced f32 weights dump (overlaps PV)
    {
      float* dst = w_out + ((size_t)bh * LL + qt * 64 + drow) * LL + kt * 64 + dcol;
      const float* sp = &lWf32[drow][dcol];
      *(float4*)(dst)      = *(const float4*)(sp);
      *(float4*)(dst + 4)  = *(const float4*)(sp + 4);
      *(float4*)(dst + 8)  = *(const float4*)(sp + 8);
      *(float4*)(dst + 12) = *(const float4*)(sp + 12);
    }
    // PV: A = W (wave's 16 rows), B = V^T
    bhalf8 aw0 = *(const bhalf8*)&lW[w * 16 + lr][kg * 8];
    bhalf8 aw1 = *(const bhalf8*)&lW[w * 16 + lr][32 + kg * 8];
#pragma unroll
    for (int n = 0; n < 4; ++n) {
      const unsigned short* vp = vtb + (size_t)(n * 16 + lr) * LL + kt * 64 + kg * 8;
      bhalf8 bv0 = *(const bhalf8*)vp;
      bhalf8 bv1 = *(const bhalf8*)(vp + 32);
      oacc[n] = __builtin_amdgcn_mfma_f32_16x16x32_bf16(aw0, bv0, oacc[n], 0, 0, 0);
      oacc[n] = __builtin_amdgcn_mfma_f32_16x16x32_bf16(aw1, bv1, oacc[n], 0, 0, 0);
    }
  }
  const int b = bh >> 4, h = bh & 15;
#pragma unroll
  for (int n = 0; n < 4; ++n)
#pragma unroll
    for (int r = 0; r < 4; ++r)
      attn_bf[(size_t)(b * LL + myrow[r]) * DD + h * DH + n * 16 + lr] = f2bf(oacc[n][r]);
}

// ---------- launch ----------
extern "C" void kernel_launch(void* const* d_in, const int* in_sizes, int n_in,
                              void* d_out, int out_size, void* d_ws, size_t ws_size,
                              hipStream_t stream) {
  const float* query = (const float*)d_in[0];
  const float* key   = (const float*)d_in[1];
  const float* value = (const float*)d_in[2];
  // d_in[3] = mask (tril, implemented analytically)
  const float* Wq = (const float*)d_in[4];
  const float* bq = (const float*)d_in[5];
  const float* Wo = (const float*)d_in[6];
  const float* bo = (const float*)d_in[7];
  const float* rel = (const float*)d_in[8];

  if (ws_size < WS_NEED) return;

  char* ws = (char*)d_ws;
  unsigned short* Xbf    = (unsigned short*)(ws + OFF_XBF);
  unsigned short* Wqbf   = (unsigned short*)(ws + OFF_WQBF);
  unsigned short* Wobf   = (unsigned short*)(ws + OFF_WOBF);
  unsigned short* q_bf   = (unsigned short*)(ws + OFF_QBF);
  unsigned short* k_bf   = (unsigned short*)(ws + OFF_KBF);
  unsigned short* vt_bf  = (unsigned short*)(ws + OFF_VTBF);
  unsigned short* attnbf = (unsigned short*)(ws + OFF_ATTNBF);
  float* wAS   = (float*)(ws + OFF_WAS);
  float* bAS   = (float*)(ws + OFF_BAS);
  float* A_arr = (float*)(ws + OFF_AARR);
  float* S_arr = (float*)(ws + OFF_SARR);
  float* M_arr = (float*)(ws + OFF_MARR);
  float* Z_arr = (float*)(ws + OFF_ZARR);

  float* out0 = (float*)d_out;
  float* w_out = out0 + (size_t)MOUT * DD;   // weights region

  cast_f32_bf16<<<4096, 256, 0, stream>>>(query, Xbf, 1048576);
  cast_f32_bf16<<<4096, 256, 0, stream>>>(key,   Xbf + (size_t)MOUT * DD, 1048576);
  cast_f32_bf16<<<4096, 256, 0, stream>>>(value, Xbf + (size_t)2 * MOUT * DD, 1048576);
  cast_f32_bf16<<<1024, 256, 0, stream>>>(Wq, Wqbf, 262144);
  cast_f32_bf16<<<1024, 256, 0, stream>>>(Wo, Wobf, 262144);

  prep_rel<<<128, 256, 0, stream>>>(Wq, bq, rel, wAS, bAS);
  rel_AS<<<512, 256, 0, stream>>>(query, wAS, bAS, A_arr, S_arr);

  gemm_bt<0><<<dim3(96, 8), 256, 0, stream>>>(Xbf, Wqbf, bq, q_bf, k_bf, vt_bf, nullptr);

  attn_a<<<1024, 256, 0, stream>>>(q_bf, k_bf, A_arr, S_arr, M_arr, Z_arr);
  attn_b<<<1024, 256, 0, stream>>>(q_bf, k_bf, vt_bf, A_arr, S_arr, M_arr, Z_arr,
                                   w_out, attnbf);

  gemm_bt<1><<<dim3(32, 8), 256, 0, stream>>>(attnbf, Wobf, bo, nullptr, nullptr, nullptr, out0);
}

// Round 5
// 1028.918 us; speedup vs baseline: 1.2425x; 1.2425x over previous
//
#include <hip/hip_runtime.h>
#include <cstdint>

// ---------- constants ----------
#define BB 2
#define LL 2048
#define DD 1024
#define HH 16
#define DH 64
#define BH 32          // B*H
#define MPROJ 12288    // 3*B*L
#define MOUT 4096      // B*L

typedef __attribute__((ext_vector_type(8))) short bhalf8;   // 8 bf16
typedef __attribute__((ext_vector_type(4))) float f32x4;

__device__ __forceinline__ unsigned short f2bf(float f) {
  union { float f; unsigned u; } c; c.f = f;
  unsigned u = c.u;
  u = (u + 0x7fffu + ((u >> 16) & 1u)) >> 16;
  return (unsigned short)u;
}

// ---------- workspace layout (bytes) ----------
constexpr size_t OFF_XBF    = 0;                                  // 12288*1024 bf16
constexpr size_t OFF_WQBF   = OFF_XBF    + (size_t)MPROJ*DD*2;
constexpr size_t OFF_WOBF   = OFF_WQBF   + (size_t)DD*DD*2;
constexpr size_t OFF_QBF    = OFF_WOBF   + (size_t)DD*DD*2;       // [bh][l][d]
constexpr size_t OFF_KBF    = OFF_QBF    + (size_t)BH*LL*DH*2;
constexpr size_t OFF_VTBF   = OFF_KBF    + (size_t)BH*LL*DH*2;    // [bh][d][l]
constexpr size_t OFF_ATTNBF = OFF_VTBF   + (size_t)BH*LL*DH*2;    // [b*L+l][D]
constexpr size_t OFF_WAS    = OFF_ATTNBF + (size_t)MOUT*DD*2;     // [2][16][1024] f32
constexpr size_t OFF_BAS    = OFF_WAS    + (size_t)2*HH*DD*4;
constexpr size_t OFF_AARR   = OFF_BAS    + 256;                   // [bh][l] f32
constexpr size_t OFF_SARR   = OFF_AARR   + (size_t)BH*LL*4;
constexpr size_t OFF_MARR   = OFF_SARR   + (size_t)BH*LL*4;
constexpr size_t OFF_ZARR   = OFF_MARR   + (size_t)BH*LL*4;
constexpr size_t WS_NEED    = OFF_ZARR   + (size_t)BH*LL*4;

// ---------- cast fp32 -> bf16 (vectorized) ----------
__global__ __launch_bounds__(256) void cast_f32_bf16(
    const float* __restrict__ src, unsigned short* __restrict__ dst, int n4) {
  int i = blockIdx.x * 256 + threadIdx.x;
  if (i < n4) {
    float4 v = ((const float4*)src)[i];
    ushort4 o;
    o.x = f2bf(v.x); o.y = f2bf(v.y); o.z = f2bf(v.z); o.w = f2bf(v.w);
    ((ushort4*)dst)[i] = o;
  }
}

// ---------- wA/wS vectors from Wq (f64 accum) ----------
__global__ __launch_bounds__(256) void prep_rel(
    const float* __restrict__ Wq, const float* __restrict__ bq,
    const float* __restrict__ rel, float* __restrict__ wAS, float* __restrict__ bAS) {
  int idx = blockIdx.x * 256 + threadIdx.x;
  if (idx >= 2 * HH * DD) return;
  int kind = idx >> 14;
  int h = (idx >> 10) & 15;
  int c = idx & 1023;
  double s = 0.0;
  for (int d = 0; d < DH; ++d) {
    double coef = kind ? 1.0 : (double)rel[d];   // rel_emb row 0
    s += coef * (double)Wq[(size_t)(h * DH + d) * DD + c];
  }
  wAS[idx] = (float)s;
  if (c == 0) {
    double b = 0.0;
    for (int d = 0; d < DH; ++d) {
      double coef = kind ? 1.0 : (double)rel[d];
      b += coef * (double)bq[h * DH + d];
    }
    bAS[kind * HH + h] = (float)b;
  }
}

// ---------- A_arr/S_arr = query @ wAS^T + bAS (f64 accum) ----------
__global__ __launch_bounds__(256) void rel_AS(
    const float* __restrict__ query, const float* __restrict__ wAS,
    const float* __restrict__ bAS, float* __restrict__ A_arr, float* __restrict__ S_arr) {
  int r = blockIdx.x * 8 + (threadIdx.x >> 5);  // global row in [0,4096)
  int j = threadIdx.x & 31;                      // kind*16 + h
  const float* qrow = query + (size_t)r * DD;
  const float* w = wAS + (size_t)j * DD;
  double s = 0.0;
  for (int k = 0; k < DD; k += 4) {
    float4 qv = *(const float4*)(qrow + k);
    float4 wv = *(const float4*)(w + k);
    s += (double)qv.x * wv.x + (double)qv.y * wv.y +
         (double)qv.z * wv.z + (double)qv.w * wv.w;
  }
  s += (double)bAS[j];
  int b = r >> 11, l = r & 2047;
  int h = j & 15;
  size_t idx = (size_t)(b * HH + h) * LL + l;
  if (j >> 4) S_arr[idx] = (float)s; else A_arr[idx] = (float)s;
}

// ---------- bf16 MFMA GEMM, C = A @ B^T + bias ----------
template <int EPI>
__global__ __launch_bounds__(256) void gemm_bt(
    const unsigned short* __restrict__ A, const unsigned short* __restrict__ Bm,
    const float* __restrict__ bias,
    unsigned short* __restrict__ q_bf, unsigned short* __restrict__ k_bf,
    unsigned short* __restrict__ vt_bf, float* __restrict__ outp) {
  __shared__ unsigned short lA[2][128 * 32];
  __shared__ unsigned short lB[2][128 * 32];
  const int bi = blockIdx.x, bj = blockIdx.y;
  const int t = threadIdx.x;
  const int w = t >> 6, lane = t & 63;
  const int lr = lane & 15, kg = lane >> 4;
  const int wr = w >> 1, wc = w & 1;

  const int srow = t >> 1, scol = (t & 1) * 16;
  const unsigned short* gA = A + (size_t)(bi * 128 + srow) * DD + scol;
  const unsigned short* gB = Bm + (size_t)(bj * 128 + srow) * DD + scol;
  const int soff = srow * 32 + scol;

  const f32x4 Z4 = {0.f, 0.f, 0.f, 0.f};
  f32x4 acc[4][4];
#pragma unroll
  for (int m = 0; m < 4; ++m)
#pragma unroll
    for (int n = 0; n < 4; ++n) acc[m][n] = Z4;

  {
    uint4 ra0 = *(const uint4*)(gA);
    uint4 ra1 = *(const uint4*)(gA + 8);
    uint4 rb0 = *(const uint4*)(gB);
    uint4 rb1 = *(const uint4*)(gB + 8);
    *(uint4*)&lA[0][soff] = ra0; *(uint4*)&lA[0][soff + 8] = ra1;
    *(uint4*)&lB[0][soff] = rb0; *(uint4*)&lB[0][soff + 8] = rb1;
  }
  __syncthreads();

  int cur = 0;
  for (int kt = 0; kt < 32; ++kt) {
    uint4 ra0, ra1, rb0, rb1;
    const bool more = (kt + 1 < 32);
    if (more) {
      const int k0 = (kt + 1) * 32;
      ra0 = *(const uint4*)(gA + k0);
      ra1 = *(const uint4*)(gA + k0 + 8);
      rb0 = *(const uint4*)(gB + k0);
      rb1 = *(const uint4*)(gB + k0 + 8);
    }
    bhalf8 af[4], bf[4];
#pragma unroll
    for (int m = 0; m < 4; ++m)
      af[m] = *(const bhalf8*)&lA[cur][(wr * 64 + m * 16 + lr) * 32 + kg * 8];
#pragma unroll
    for (int n = 0; n < 4; ++n)
      bf[n] = *(const bhalf8*)&lB[cur][(wc * 64 + n * 16 + lr) * 32 + kg * 8];
#pragma unroll
    for (int m = 0; m < 4; ++m)
#pragma unroll
      for (int n = 0; n < 4; ++n)
        acc[m][n] = __builtin_amdgcn_mfma_f32_16x16x32_bf16(af[m], bf[n], acc[m][n], 0, 0, 0);
    if (more) {
      *(uint4*)&lA[cur ^ 1][soff] = ra0; *(uint4*)&lA[cur ^ 1][soff + 8] = ra1;
      *(uint4*)&lB[cur ^ 1][soff] = rb0; *(uint4*)&lB[cur ^ 1][soff + 8] = rb1;
    }
    __syncthreads();
    cur ^= 1;
  }

  // epilogue
#pragma unroll
  for (int n = 0; n < 4; ++n) {
    const int gcol = bj * 128 + wc * 64 + n * 16 + lr;
    const float bv = bias[gcol];
#pragma unroll
    for (int m = 0; m < 4; ++m) {
#pragma unroll
      for (int r = 0; r < 4; ++r) {
        const int grow = bi * 128 + wr * 64 + m * 16 + kg * 4 + r;
        float v = acc[m][n][r] + bv;
        if (EPI == 0) {
          const int src = grow >> 12;
          const int rl = grow & 4095;
          const int b = rl >> 11, l2 = rl & 2047;
          const int h = gcol >> 6, d = gcol & 63;
          const int bh = b * HH + h;
          unsigned short bfv = f2bf(v);
          if (src == 0)      q_bf[((size_t)bh * LL + l2) * DH + d] = bfv;
          else if (src == 1) k_bf[((size_t)bh * LL + l2) * DH + d] = bfv;
          else               vt_bf[((size_t)bh * DH + d) * LL + l2] = bfv;
        } else {
          outp[(size_t)grow * DD + gcol] = v;
        }
      }
    }
  }
}

// K-tile LDS swizzle: chunk' = chunk ^ (row&7)  (byte ^= (row&7)<<4)

// ---------- attention phase A: per-row max and 1/sum ----------
// Heavy-first block order + double-buffered K + single barrier per tile.
__global__ __launch_bounds__(256) void attn_a(
    const unsigned short* __restrict__ q_bf, const unsigned short* __restrict__ k_bf,
    const float* __restrict__ A_arr, const float* __restrict__ S_arr,
    float* __restrict__ M_arr, float* __restrict__ Zinv_arr) {
  __shared__ unsigned short lK[2][64 * 64];
  const int bid = blockIdx.x;
  const int bh = bid & 31, qt = 31 - (bid >> 5);   // heavy blocks launch first
  const int t = threadIdx.x, w = t >> 6, lane = t & 63;
  const int lr = lane & 15, kg = lane >> 4;
  const int qrow0 = qt * 64 + w * 16;

  const unsigned short* qbase = q_bf + ((size_t)bh * LL + qrow0 + lr) * DH + kg * 8;
  bhalf8 aq0 = *(const bhalf8*)qbase;
  bhalf8 aq1 = *(const bhalf8*)(qbase + 32);

  float Av[4], Sv[4], Mr[4], ps[4];
  int myrow[4];
#pragma unroll
  for (int r = 0; r < 4; ++r) {
    myrow[r] = qrow0 + kg * 4 + r;
    Av[r] = A_arr[(size_t)bh * LL + myrow[r]];
    Sv[r] = S_arr[(size_t)bh * LL + myrow[r]];
    Mr[r] = -INFINITY; ps[r] = 0.f;
  }

  const int srow = t >> 2, scol = (t & 3) * 16;
  const int se0 = srow * 64 + ((((t & 3) * 2 + 0) ^ (srow & 7)) * 8);
  const int se1 = srow * 64 + ((((t & 3) * 2 + 1) ^ (srow & 7)) * 8);
  const unsigned short* kbase = k_bf + (size_t)bh * LL * DH;
  const f32x4 Z4 = {0.f, 0.f, 0.f, 0.f};

  // prologue: stage K(0) into buf 0
  {
    const unsigned short* src = kbase + (size_t)srow * DH + scol;
    uint4 v0 = *(const uint4*)src;
    uint4 v1 = *(const uint4*)(src + 8);
    *(uint4*)&lK[0][se0] = v0;
    *(uint4*)&lK[0][se1] = v1;
  }

  int cur = 0;
  for (int kt = 0; kt <= qt; ++kt) {
    __syncthreads();                       // lK[cur] ready; prev reads drained
    uint4 n0, n1;
    const bool more = (kt < qt);
    if (more) {                            // prefetch K(kt+1) into regs
      const unsigned short* src = kbase + (size_t)((kt + 1) * 64 + srow) * DH + scol;
      n0 = *(const uint4*)src;
      n1 = *(const uint4*)(src + 8);
    }
    f32x4 acc[4];
#pragma unroll
    for (int n = 0; n < 4; ++n) {
      acc[n] = Z4;
      const int rowb = n * 16 + lr;
      bhalf8 b0 = *(const bhalf8*)&lK[cur][rowb * 64 + ((kg ^ (rowb & 7)) * 8)];
      bhalf8 b1 = *(const bhalf8*)&lK[cur][rowb * 64 + (((4 + kg) ^ (rowb & 7)) * 8)];
      acc[n] = __builtin_amdgcn_mfma_f32_16x16x32_bf16(aq0, b0, acc[n], 0, 0, 0);
      acc[n] = __builtin_amdgcn_mfma_f32_16x16x32_bf16(aq1, b1, acc[n], 0, 0, 0);
    }
    float lg[4][4];
#pragma unroll
    for (int n = 0; n < 4; ++n) {
      const int gcol = kt * 64 + n * 16 + lr;
#pragma unroll
      for (int r = 0; r < 4; ++r) {
        float rel = Av[r] - (float)(2047 - myrow[r] + gcol) * Sv[r];
        float l = (acc[n][r] + rel) * 0.125f;
        lg[n][r] = (gcol <= myrow[r]) ? l : -1e30f;
      }
    }
#pragma unroll
    for (int r = 0; r < 4; ++r) {
      float tmax = fmaxf(fmaxf(lg[0][r], lg[1][r]), fmaxf(lg[2][r], lg[3][r]));
      tmax = fmaxf(tmax, __shfl_xor(tmax, 1));
      tmax = fmaxf(tmax, __shfl_xor(tmax, 2));
      tmax = fmaxf(tmax, __shfl_xor(tmax, 4));
      tmax = fmaxf(tmax, __shfl_xor(tmax, 8));
      float Mn = fmaxf(Mr[r], tmax);
      float s = ps[r] * __expf(Mr[r] - Mn);
      s += __expf(lg[0][r] - Mn) + __expf(lg[1][r] - Mn) +
           __expf(lg[2][r] - Mn) + __expf(lg[3][r] - Mn);
      ps[r] = s; Mr[r] = Mn;
    }
    if (more) {                            // write prefetched tile to other buf
      *(uint4*)&lK[cur ^ 1][se0] = n0;
      *(uint4*)&lK[cur ^ 1][se1] = n1;
    }
    cur ^= 1;
  }
#pragma unroll
  for (int r = 0; r < 4; ++r) {
    float s = ps[r];
    s += __shfl_xor(s, 1); s += __shfl_xor(s, 2);
    s += __shfl_xor(s, 4); s += __shfl_xor(s, 8);
    if (lr == 0) {
      M_arr[(size_t)bh * LL + myrow[r]] = Mr[r];
      Zinv_arr[(size_t)bh * LL + myrow[r]] = 1.0f / s;
    }
  }
}

// ---------- attention phase B: weights write + PV ----------
// lW is wave-private (wave w writes & reads rows w*16..w*16+15) -> no barrier
// between lW write and PV read; single barrier per tile via double-buffered lK.
__global__ __launch_bounds__(256) void attn_b(
    const unsigned short* __restrict__ q_bf, const unsigned short* __restrict__ k_bf,
    const unsigned short* __restrict__ vt_bf,
    const float* __restrict__ A_arr, const float* __restrict__ S_arr,
    const float* __restrict__ M_arr, const float* __restrict__ Zinv_arr,
    float* __restrict__ w_out, unsigned short* __restrict__ attn_bf) {
  __shared__ unsigned short lK[2][64 * 64];
  __shared__ unsigned short lW[64][72];   // bf16 weights for PV (+8 pad)
  const int bid = blockIdx.x;
  const int bh = bid & 31, qt = 31 - (bid >> 5);   // heavy blocks launch first
  const int t = threadIdx.x, w = t >> 6, lane = t & 63;
  const int lr = lane & 15, kg = lane >> 4;
  const int qrow0 = qt * 64 + w * 16;

  const unsigned short* qbase = q_bf + ((size_t)bh * LL + qrow0 + lr) * DH + kg * 8;
  bhalf8 aq0 = *(const bhalf8*)qbase;
  bhalf8 aq1 = *(const bhalf8*)(qbase + 32);

  float Av[4], Sv[4], Mv[4], Zv[4];
  int myrow[4];
#pragma unroll
  for (int r = 0; r < 4; ++r) {
    myrow[r] = qrow0 + kg * 4 + r;
    Av[r] = A_arr[(size_t)bh * LL + myrow[r]];
    Sv[r] = S_arr[(size_t)bh * LL + myrow[r]];
    Mv[r] = M_arr[(size_t)bh * LL + myrow[r]];
    Zv[r] = Zinv_arr[(size_t)bh * LL + myrow[r]];
  }

  const f32x4 Z4 = {0.f, 0.f, 0.f, 0.f};
  f32x4 oacc[4];
#pragma unroll
  for (int n = 0; n < 4; ++n) oacc[n] = Z4;

  const int srow = t >> 2, scol = (t & 3) * 16;
  const int se0 = srow * 64 + ((((t & 3) * 2 + 0) ^ (srow & 7)) * 8);
  const int se1 = srow * 64 + ((((t & 3) * 2 + 1) ^ (srow & 7)) * 8);
  const unsigned short* kbase = k_bf + (size_t)bh * LL * DH;
  const unsigned short* vtb = vt_bf + (size_t)bh * DH * LL;

  // masked tiles: barrier-free coalesced zero fill
  for (int kt = qt + 1; kt < 32; ++kt) {
    float* dst = w_out + ((size_t)bh * LL + qt * 64 + srow) * LL + kt * 64 + scol;
    float4 z = make_float4(0.f, 0.f, 0.f, 0.f);
    *(float4*)(dst) = z; *(float4*)(dst + 4) = z;
    *(float4*)(dst + 8) = z; *(float4*)(dst + 12) = z;
  }

  // prologue: stage K(0) into buf 0
  {
    const unsigned short* src = kbase + (size_t)srow * DH + scol;
    uint4 v0 = *(const uint4*)src;
    uint4 v1 = *(const uint4*)(src + 8);
    *(uint4*)&lK[0][se0] = v0;
    *(uint4*)&lK[0][se1] = v1;
  }

  int cur = 0;
  for (int kt = 0; kt <= qt; ++kt) {
    __syncthreads();                       // lK[cur] ready; prev reads drained
    uint4 n0, n1;
    const bool more = (kt < qt);
    if (more) {                            // prefetch K(kt+1) into regs
      const unsigned short* src = kbase + (size_t)((kt + 1) * 64 + srow) * DH + scol;
      n0 = *(const uint4*)src;
      n1 = *(const uint4*)(src + 8);
    }
    f32x4 acc[4];
#pragma unroll
    for (int n = 0; n < 4; ++n) {
      acc[n] = Z4;
      const int rowb = n * 16 + lr;
      bhalf8 b0 = *(const bhalf8*)&lK[cur][rowb * 64 + ((kg ^ (rowb & 7)) * 8)];
      bhalf8 b1 = *(const bhalf8*)&lK[cur][rowb * 64 + (((4 + kg) ^ (rowb & 7)) * 8)];
      acc[n] = __builtin_amdgcn_mfma_f32_16x16x32_bf16(aq0, b0, acc[n], 0, 0, 0);
      acc[n] = __builtin_amdgcn_mfma_f32_16x16x32_bf16(aq1, b1, acc[n], 0, 0, 0);
    }
#pragma unroll
    for (int n = 0; n < 4; ++n) {
      const int gcol = kt * 64 + n * 16 + lr;
#pragma unroll
      for (int r = 0; r < 4; ++r) {
        float rel = Av[r] - (float)(2047 - myrow[r] + gcol) * Sv[r];
        float l = (acc[n][r] + rel) * 0.125f;
        float wgt = (gcol <= myrow[r]) ? __expf(l - Mv[r]) * Zv[r] : 0.f;
        lW[w * 16 + kg * 4 + r][n * 16 + lr] = f2bf(wgt);
        w_out[((size_t)bh * LL + myrow[r]) * LL + gcol] = wgt;   // fp32, exact
      }
    }
    // PV: lW rows are this wave's own -> no __syncthreads needed
    bhalf8 aw0 = *(const bhalf8*)&lW[w * 16 + lr][kg * 8];
    bhalf8 aw1 = *(const bhalf8*)&lW[w * 16 + lr][32 + kg * 8];
#pragma unroll
    for (int n = 0; n < 4; ++n) {
      const unsigned short* vp = vtb + (size_t)(n * 16 + lr) * LL + kt * 64 + kg * 8;
      bhalf8 bv0 = *(const bhalf8*)vp;
      bhalf8 bv1 = *(const bhalf8*)(vp + 32);
      oacc[n] = __builtin_amdgcn_mfma_f32_16x16x32_bf16(aw0, bv0, oacc[n], 0, 0, 0);
      oacc[n] = __builtin_amdgcn_mfma_f32_16x16x32_bf16(aw1, bv1, oacc[n], 0, 0, 0);
    }
    if (more) {                            // write prefetched tile to other buf
      *(uint4*)&lK[cur ^ 1][se0] = n0;
      *(uint4*)&lK[cur ^ 1][se1] = n1;
    }
    cur ^= 1;
  }
  const int b = bh >> 4, h = bh & 15;
#pragma unroll
  for (int n = 0; n < 4; ++n)
#pragma unroll
    for (int r = 0; r < 4; ++r)
      attn_bf[(size_t)(b * LL + myrow[r]) * DD + h * DH + n * 16 + lr] = f2bf(oacc[n][r]);
}

// ---------- launch ----------
extern "C" void kernel_launch(void* const* d_in, const int* in_sizes, int n_in,
                              void* d_out, int out_size, void* d_ws, size_t ws_size,
                              hipStream_t stream) {
  const float* query = (const float*)d_in[0];
  const float* key   = (const float*)d_in[1];
  const float* value = (const float*)d_in[2];
  // d_in[3] = mask (tril, implemented analytically)
  const float* Wq = (const float*)d_in[4];
  const float* bq = (const float*)d_in[5];
  const float* Wo = (const float*)d_in[6];
  const float* bo = (const float*)d_in[7];
  const float* rel = (const float*)d_in[8];

  if (ws_size < WS_NEED) return;

  char* ws = (char*)d_ws;
  unsigned short* Xbf    = (unsigned short*)(ws + OFF_XBF);
  unsigned short* Wqbf   = (unsigned short*)(ws + OFF_WQBF);
  unsigned short* Wobf   = (unsigned short*)(ws + OFF_WOBF);
  unsigned short* q_bf   = (unsigned short*)(ws + OFF_QBF);
  unsigned short* k_bf   = (unsigned short*)(ws + OFF_KBF);
  unsigned short* vt_bf  = (unsigned short*)(ws + OFF_VTBF);
  unsigned short* attnbf = (unsigned short*)(ws + OFF_ATTNBF);
  float* wAS   = (float*)(ws + OFF_WAS);
  float* bAS   = (float*)(ws + OFF_BAS);
  float* A_arr = (float*)(ws + OFF_AARR);
  float* S_arr = (float*)(ws + OFF_SARR);
  float* M_arr = (float*)(ws + OFF_MARR);
  float* Z_arr = (float*)(ws + OFF_ZARR);

  float* out0 = (float*)d_out;
  float* w_out = out0 + (size_t)MOUT * DD;   // weights region

  cast_f32_bf16<<<4096, 256, 0, stream>>>(query, Xbf, 1048576);
  cast_f32_bf16<<<4096, 256, 0, stream>>>(key,   Xbf + (size_t)MOUT * DD, 1048576);
  cast_f32_bf16<<<4096, 256, 0, stream>>>(value, Xbf + (size_t)2 * MOUT * DD, 1048576);
  cast_f32_bf16<<<1024, 256, 0, stream>>>(Wq, Wqbf, 262144);
  cast_f32_bf16<<<1024, 256, 0, stream>>>(Wo, Wobf, 262144);

  prep_rel<<<128, 256, 0, stream>>>(Wq, bq, rel, wAS, bAS);
  rel_AS<<<512, 256, 0, stream>>>(query, wAS, bAS, A_arr, S_arr);

  gemm_bt<0><<<dim3(96, 8), 256, 0, stream>>>(Xbf, Wqbf, bq, q_bf, k_bf, vt_bf, nullptr);

  attn_a<<<1024, 256, 0, stream>>>(q_bf, k_bf, A_arr, S_arr, M_arr, Z_arr);
  attn_b<<<1024, 256, 0, stream>>>(q_bf, k_bf, vt_bf, A_arr, S_arr, M_arr, Z_arr,
                                   w_out, attnbf);

  gemm_bt<1><<<dim3(32, 8), 256, 0, stream>>>(attnbf, Wobf, bo, nullptr, nullptr, nullptr, out0);
}

// Round 7
// 1017.810 us; speedup vs baseline: 1.2561x; 1.0109x over previous
//
#include <hip/hip_runtime.h>
#include <cstdint>

// ---------- constants ----------
#define BB 2
#define LL 2048
#define DD 1024
#define HH 16
#define DH 64
#define BH 32          // B*H
#define MPROJ 12288    // 3*B*L
#define MOUT 4096      // B*L

typedef __attribute__((ext_vector_type(8))) short bhalf8;   // 8 bf16
typedef __attribute__((ext_vector_type(4))) float f32x4;

__device__ __forceinline__ unsigned short f2bf(float f) {
  union { float f; unsigned u; } c; c.f = f;
  unsigned u = c.u;
  u = (u + 0x7fffu + ((u >> 16) & 1u)) >> 16;
  return (unsigned short)u;
}

// async global->LDS DMA, 16B per lane. LDS dest = wave-uniform base + lane*16.
__device__ __forceinline__ void async_copy16(void* lds, const void* g) {
  __builtin_amdgcn_global_load_lds(
      (const __attribute__((address_space(1))) unsigned int*)g,
      (__attribute__((address_space(3))) unsigned int*)lds, 16, 0, 0);
}

// ---------- workspace layout (bytes) ----------
constexpr size_t OFF_XBF    = 0;                                  // 12288*1024 bf16
constexpr size_t OFF_WQBF   = OFF_XBF    + (size_t)MPROJ*DD*2;
constexpr size_t OFF_WOBF   = OFF_WQBF   + (size_t)DD*DD*2;
constexpr size_t OFF_QBF    = OFF_WOBF   + (size_t)DD*DD*2;       // [bh][l][d]
constexpr size_t OFF_KBF    = OFF_QBF    + (size_t)BH*LL*DH*2;
constexpr size_t OFF_VTBF   = OFF_KBF    + (size_t)BH*LL*DH*2;    // [bh][d][l]
constexpr size_t OFF_ATTNBF = OFF_VTBF   + (size_t)BH*LL*DH*2;    // [b*L+l][D]
constexpr size_t OFF_WAS    = OFF_ATTNBF + (size_t)MOUT*DD*2;     // [2][16][1024] f32
constexpr size_t OFF_BAS    = OFF_WAS    + (size_t)2*HH*DD*4;
constexpr size_t OFF_AARR   = OFF_BAS    + 256;                   // [bh][l] f32
constexpr size_t OFF_SARR   = OFF_AARR   + (size_t)BH*LL*4;
constexpr size_t OFF_MARR   = OFF_SARR   + (size_t)BH*LL*4;
constexpr size_t OFF_ZARR   = OFF_MARR   + (size_t)BH*LL*4;
constexpr size_t WS_NEED    = OFF_ZARR   + (size_t)BH*LL*4;

// ---------- cast fp32 -> bf16 (vectorized) ----------
__global__ __launch_bounds__(256) void cast_f32_bf16(
    const float* __restrict__ src, unsigned short* __restrict__ dst, int n4) {
  int i = blockIdx.x * 256 + threadIdx.x;
  if (i < n4) {
    float4 v = ((const float4*)src)[i];
    ushort4 o;
    o.x = f2bf(v.x); o.y = f2bf(v.y); o.z = f2bf(v.z); o.w = f2bf(v.w);
    ((ushort4*)dst)[i] = o;
  }
}

// ---------- wA/wS vectors from Wq (f64 accum) ----------
__global__ __launch_bounds__(256) void prep_rel(
    const float* __restrict__ Wq, const float* __restrict__ bq,
    const float* __restrict__ rel, float* __restrict__ wAS, float* __restrict__ bAS) {
  int idx = blockIdx.x * 256 + threadIdx.x;
  if (idx >= 2 * HH * DD) return;
  int kind = idx >> 14;
  int h = (idx >> 10) & 15;
  int c = idx & 1023;
  double s = 0.0;
  for (int d = 0; d < DH; ++d) {
    double coef = kind ? 1.0 : (double)rel[d];   // rel_emb row 0
    s += coef * (double)Wq[(size_t)(h * DH + d) * DD + c];
  }
  wAS[idx] = (float)s;
  if (c == 0) {
    double b = 0.0;
    for (int d = 0; d < DH; ++d) {
      double coef = kind ? 1.0 : (double)rel[d];
      b += coef * (double)bq[h * DH + d];
    }
    bAS[kind * HH + h] = (float)b;
  }
}

// ---------- A_arr/S_arr = query @ wAS^T + bAS (f64 accum) ----------
__global__ __launch_bounds__(256) void rel_AS(
    const float* __restrict__ query, const float* __restrict__ wAS,
    const float* __restrict__ bAS, float* __restrict__ A_arr, float* __restrict__ S_arr) {
  int r = blockIdx.x * 8 + (threadIdx.x >> 5);  // global row in [0,4096)
  int j = threadIdx.x & 31;                      // kind*16 + h
  const float* qrow = query + (size_t)r * DD;
  const float* w = wAS + (size_t)j * DD;
  double s = 0.0;
  for (int k = 0; k < DD; k += 4) {
    float4 qv = *(const float4*)(qrow + k);
    float4 wv = *(const float4*)(w + k);
    s += (double)qv.x * wv.x + (double)qv.y * wv.y +
         (double)qv.z * wv.z + (double)qv.w * wv.w;
  }
  s += (double)bAS[j];
  int b = r >> 11, l = r & 2047;
  int h = j & 15;
  size_t idx = (size_t)(b * HH + h) * LL + l;
  if (j >> 4) S_arr[idx] = (float)s; else A_arr[idx] = (float)s;
}

// ---------- bf16 MFMA GEMM, C = A @ B^T + bias (global_load_lds staging) ----------
template <int EPI>
__global__ __launch_bounds__(256) void gemm_bt(
    const unsigned short* __restrict__ A, const unsigned short* __restrict__ Bm,
    const float* __restrict__ bias,
    unsigned short* __restrict__ q_bf, unsigned short* __restrict__ k_bf,
    unsigned short* __restrict__ vt_bf, float* __restrict__ outp) {
  __shared__ unsigned short lA[2][128 * 32];
  __shared__ unsigned short lB[2][128 * 32];
  const int bi = blockIdx.x, bj = blockIdx.y;
  const int t = threadIdx.x;
  const int w = t >> 6, lane = t & 63;
  const int lr = lane & 15, kg = lane >> 4;
  const int wr = w >> 1, wc = w & 1;

  const unsigned short* gAb = A + (size_t)(bi * 128) * DD;
  const unsigned short* gBb = Bm + (size_t)(bj * 128) * DD;
  // DMA chunk c = w*128 + i*64 + lane; LDS linear [128][32]: row=c>>2, 16B-quarter q=c&3
  const int c0 = w * 128 + lane;
  const int row0 = c0 >> 2, q0 = (c0 & 3) * 8;
  const int row1 = (c0 + 64) >> 2, q1 = ((c0 + 64) & 3) * 8;

  const f32x4 Z4 = {0.f, 0.f, 0.f, 0.f};
  f32x4 acc[4][4];
#pragma unroll
  for (int m = 0; m < 4; ++m)
#pragma unroll
    for (int n = 0; n < 4; ++n) acc[m][n] = Z4;

  // prologue: stage K-tile 0 into buf 0
  {
    async_copy16(&lA[0][(w * 128) * 8],      gAb + (size_t)row0 * DD + q0);
    async_copy16(&lA[0][(w * 128 + 64) * 8], gAb + (size_t)row1 * DD + q1);
    async_copy16(&lB[0][(w * 128) * 8],      gBb + (size_t)row0 * DD + q0);
    async_copy16(&lB[0][(w * 128 + 64) * 8], gBb + (size_t)row1 * DD + q1);
  }

  int cur = 0;
  for (int kt = 0; kt < 32; ++kt) {
    __syncthreads();                         // drains vmcnt -> buf[cur] ready
    if (kt + 1 < 32) {                       // async stage next tile
      const int k0 = (kt + 1) * 32;
      async_copy16(&lA[cur ^ 1][(w * 128) * 8],      gAb + (size_t)row0 * DD + k0 + q0);
      async_copy16(&lA[cur ^ 1][(w * 128 + 64) * 8], gAb + (size_t)row1 * DD + k0 + q1);
      async_copy16(&lB[cur ^ 1][(w * 128) * 8],      gBb + (size_t)row0 * DD + k0 + q0);
      async_copy16(&lB[cur ^ 1][(w * 128 + 64) * 8], gBb + (size_t)row1 * DD + k0 + q1);
    }
    bhalf8 af[4], bf[4];
#pragma unroll
    for (int m = 0; m < 4; ++m)
      af[m] = *(const bhalf8*)&lA[cur][(wr * 64 + m * 16 + lr) * 32 + kg * 8];
#pragma unroll
    for (int n = 0; n < 4; ++n)
      bf[n] = *(const bhalf8*)&lB[cur][(wc * 64 + n * 16 + lr) * 32 + kg * 8];
#pragma unroll
    for (int m = 0; m < 4; ++m)
#pragma unroll
      for (int n = 0; n < 4; ++n)
        acc[m][n] = __builtin_amdgcn_mfma_f32_16x16x32_bf16(af[m], bf[n], acc[m][n], 0, 0, 0);
    cur ^= 1;
  }

  // epilogue
#pragma unroll
  for (int n = 0; n < 4; ++n) {
    const int gcol = bj * 128 + wc * 64 + n * 16 + lr;
    const float bv = bias[gcol];
#pragma unroll
    for (int m = 0; m < 4; ++m) {
#pragma unroll
      for (int r = 0; r < 4; ++r) {
        const int grow = bi * 128 + wr * 64 + m * 16 + kg * 4 + r;
        float v = acc[m][n][r] + bv;
        if (EPI == 0) {
          const int src = grow >> 12;
          const int rl = grow & 4095;
          const int b = rl >> 11, l2 = rl & 2047;
          const int h = gcol >> 6, d = gcol & 63;
          const int bh = b * HH + h;
          unsigned short bfv = f2bf(v);
          if (src == 0)      q_bf[((size_t)bh * LL + l2) * DH + d] = bfv;
          else if (src == 1) k_bf[((size_t)bh * LL + l2) * DH + d] = bfv;
          else               vt_bf[((size_t)bh * DH + d) * LL + l2] = bfv;
        } else {
          outp[(size_t)grow * DD + gcol] = v;
        }
      }
    }
  }
}

// K-tile LDS swizzle (16B chunks): LDS chunk (row,ch) holds global chunk ch^(row&7).
// DMA writes linearly; source address pre-swizzled; reads apply the same XOR.

// ---------- attention phase A: per-row max and 1/sum ----------
// Per-lane online max/sum (no cross-lane in loop); heavy-first; DMA dbuf K.
__global__ __launch_bounds__(256) void attn_a(
    const unsigned short* __restrict__ q_bf, const unsigned short* __restrict__ k_bf,
    const float* __restrict__ A_arr, const float* __restrict__ S_arr,
    float* __restrict__ M_arr, float* __restrict__ Zinv_arr) {
  __shared__ unsigned short lK[2][64 * 64];
  const int bid = blockIdx.x;
  const int bh = bid & 31, qt = 31 - (bid >> 5);   // heavy blocks launch first
  const int t = threadIdx.x, w = t >> 6, lane = t & 63;
  const int lr = lane & 15, kg = lane >> 4;
  const int qrow0 = qt * 64 + w * 16;

  const unsigned short* qbase = q_bf + ((size_t)bh * LL + qrow0 + lr) * DH + kg * 8;
  bhalf8 aq0 = *(const bhalf8*)qbase;
  bhalf8 aq1 = *(const bhalf8*)(qbase + 32);

  float Av[4], Sv[4], Ml[4], sl[4];
  int myrow[4];
#pragma unroll
  for (int r = 0; r < 4; ++r) {
    myrow[r] = qrow0 + kg * 4 + r;
    Av[r] = A_arr[(size_t)bh * LL + myrow[r]];
    Sv[r] = S_arr[(size_t)bh * LL + myrow[r]];
    Ml[r] = -INFINITY; sl[r] = 0.f;
  }

  const unsigned short* kbase = k_bf + (size_t)bh * LL * DH;
  // DMA: chunk c = w*128 + i*64 + lane; row=c>>3, ch=c&7; src chunk = ch^(row&7)
  const int ca = w * 128 + lane;
  const int rowA = ca >> 3, chA = ((ca & 7) ^ (rowA & 7)) * 8;
  const int cb = ca + 64;
  const int rowB = cb >> 3, chB = ((cb & 7) ^ (rowB & 7)) * 8;
  const f32x4 Z4 = {0.f, 0.f, 0.f, 0.f};

  // prologue: stage K(0) into buf 0
  async_copy16(&lK[0][(w * 128) * 8],      kbase + (size_t)rowA * DH + chA);
  async_copy16(&lK[0][(w * 128 + 64) * 8], kbase + (size_t)rowB * DH + chB);

  int cur = 0;
  for (int kt = 0; kt <= qt; ++kt) {
    __syncthreads();                       // buf[cur] DMA drained
    if (kt < qt) {
      async_copy16(&lK[cur ^ 1][(w * 128) * 8],
                   kbase + (size_t)((kt + 1) * 64 + rowA) * DH + chA);
      async_copy16(&lK[cur ^ 1][(w * 128 + 64) * 8],
                   kbase + (size_t)((kt + 1) * 64 + rowB) * DH + chB);
    }
    f32x4 acc[4];
#pragma unroll
    for (int n = 0; n < 4; ++n) {
      acc[n] = Z4;
      const int rowb = n * 16 + lr;
      bhalf8 b0 = *(const bhalf8*)&lK[cur][rowb * 64 + ((kg ^ (rowb & 7)) * 8)];
      bhalf8 b1 = *(const bhalf8*)&lK[cur][rowb * 64 + (((4 + kg) ^ (rowb & 7)) * 8)];
      acc[n] = __builtin_amdgcn_mfma_f32_16x16x32_bf16(aq0, b0, acc[n], 0, 0, 0);
      acc[n] = __builtin_amdgcn_mfma_f32_16x16x32_bf16(aq1, b1, acc[n], 0, 0, 0);
    }
#pragma unroll
    for (int r = 0; r < 4; ++r) {
      float lg[4];
#pragma unroll
      for (int n = 0; n < 4; ++n) {
        const int gcol = kt * 64 + n * 16 + lr;
        float rel = Av[r] - (float)(2047 - myrow[r] + gcol) * Sv[r];
        float l = (acc[n][r] + rel) * 0.125f;
        lg[n] = (gcol <= myrow[r]) ? l : -1e30f;
      }
      float m4 = fmaxf(fmaxf(lg[0], lg[1]), fmaxf(lg[2], lg[3]));
      float Mn = fmaxf(Ml[r], m4);
      sl[r] = sl[r] * __expf(Ml[r] - Mn) +
              __expf(lg[0] - Mn) + __expf(lg[1] - Mn) +
              __expf(lg[2] - Mn) + __expf(lg[3] - Mn);
      Ml[r] = Mn;
    }
    cur ^= 1;
  }
  // merge 16 lanes (same kg group shares rows)
#pragma unroll
  for (int r = 0; r < 4; ++r) {
    float M = Ml[r], s = sl[r];
#pragma unroll
    for (int d = 1; d < 16; d <<= 1) {
      float Mo = __shfl_xor(M, d);
      float so = __shfl_xor(s, d);
      float Mn = fmaxf(M, Mo);
      s = s * __expf(M - Mn) + so * __expf(Mo - Mn);
      M = Mn;
    }
    if (lr == 0) {
      M_arr[(size_t)bh * LL + myrow[r]] = M;
      Zinv_arr[(size_t)bh * LL + myrow[r]] = 1.0f / s;
    }
  }
}

// ---------- attention phase B: weights write + PV ----------
__global__ __launch_bounds__(256) void attn_b(
    const unsigned short* __restrict__ q_bf, const unsigned short* __restrict__ k_bf,
    const unsigned short* __restrict__ vt_bf,
    const float* __restrict__ A_arr, const float* __restrict__ S_arr,
    const float* __restrict__ M_arr, const float* __restrict__ Zinv_arr,
    float* __restrict__ w_out, unsigned short* __restrict__ attn_bf) {
  __shared__ unsigned short lK[2][64 * 64];
  __shared__ unsigned short lW[64][72];   // bf16 weights for PV (+8 pad), wave-private rows
  const int bid = blockIdx.x;
  const int bh = bid & 31, qt = 31 - (bid >> 5);   // heavy blocks launch first
  const int t = threadIdx.x, w = t >> 6, lane = t & 63;
  const int lr = lane & 15, kg = lane >> 4;
  const int qrow0 = qt * 64 + w * 16;

  const unsigned short* qbase = q_bf + ((size_t)bh * LL + qrow0 + lr) * DH + kg * 8;
  bhalf8 aq0 = *(const bhalf8*)qbase;
  bhalf8 aq1 = *(const bhalf8*)(qbase + 32);

  float Av[4], Sv[4], Mv[4], Zv[4];
  int myrow[4];
#pragma unroll
  for (int r = 0; r < 4; ++r) {
    myrow[r] = qrow0 + kg * 4 + r;
    Av[r] = A_arr[(size_t)bh * LL + myrow[r]];
    Sv[r] = S_arr[(size_t)bh * LL + myrow[r]];
    Mv[r] = M_arr[(size_t)bh * LL + myrow[r]];
    Zv[r] = Zinv_arr[(size_t)bh * LL + myrow[r]];
  }

  const f32x4 Z4 = {0.f, 0.f, 0.f, 0.f};
  f32x4 oacc[4];
#pragma unroll
  for (int n = 0; n < 4; ++n) oacc[n] = Z4;

  const unsigned short* kbase = k_bf + (size_t)bh * LL * DH;
  const unsigned short* vtb = vt_bf + (size_t)bh * DH * LL;
  const int ca = w * 128 + lane;
  const int rowA = ca >> 3, chA = ((ca & 7) ^ (rowA & 7)) * 8;
  const int cb = ca + 64;
  const int rowB = cb >> 3, chB = ((cb & 7) ^ (rowB & 7)) * 8;

  // masked tiles: barrier-free coalesced zero fill
  const int drow = t >> 2, dcol = (t & 3) * 16;
  for (int kt = qt + 1; kt < 32; ++kt) {
    float* dst = w_out + ((size_t)bh * LL + qt * 64 + drow) * LL + kt * 64 + dcol;
    float4 z = make_float4(0.f, 0.f, 0.f, 0.f);
    *(float4*)(dst) = z; *(float4*)(dst + 4) = z;
    *(float4*)(dst + 8) = z; *(float4*)(dst + 12) = z;
  }

  // prologue: stage K(0) into buf 0
  async_copy16(&lK[0][(w * 128) * 8],      kbase + (size_t)rowA * DH + chA);
  async_copy16(&lK[0][(w * 128 + 64) * 8], kbase + (size_t)rowB * DH + chB);

  int cur = 0;
  for (int kt = 0; kt <= qt; ++kt) {
    __syncthreads();                       // buf[cur] DMA drained
    if (kt < qt) {
      async_copy16(&lK[cur ^ 1][(w * 128) * 8],
                   kbase + (size_t)((kt + 1) * 64 + rowA) * DH + chA);
      async_copy16(&lK[cur ^ 1][(w * 128 + 64) * 8],
                   kbase + (size_t)((kt + 1) * 64 + rowB) * DH + chB);
    }
    f32x4 acc[4];
#pragma unroll
    for (int n = 0; n < 4; ++n) {
      acc[n] = Z4;
      const int rowb = n * 16 + lr;
      bhalf8 b0 = *(const bhalf8*)&lK[cur][rowb * 64 + ((kg ^ (rowb & 7)) * 8)];
      bhalf8 b1 = *(const bhalf8*)&lK[cur][rowb * 64 + (((4 + kg) ^ (rowb & 7)) * 8)];
      acc[n] = __builtin_amdgcn_mfma_f32_16x16x32_bf16(aq0, b0, acc[n], 0, 0, 0);
      acc[n] = __builtin_amdgcn_mfma_f32_16x16x32_bf16(aq1, b1, acc[n], 0, 0, 0);
    }
#pragma unroll
    for (int n = 0; n < 4; ++n) {
      const int gcol = kt * 64 + n * 16 + lr;
#pragma unroll
      for (int r = 0; r < 4; ++r) {
        float rel = Av[r] - (float)(2047 - myrow[r] + gcol) * Sv[r];
        float l = (acc[n][r] + rel) * 0.125f;
        float wgt = (gcol <= myrow[r]) ? __expf(l - Mv[r]) * Zv[r] : 0.f;
        lW[w * 16 + kg * 4 + r][n * 16 + lr] = f2bf(wgt);
        w_out[((size_t)bh * LL + myrow[r]) * LL + gcol] = wgt;   // 64B segments
      }
    }
    // PV: lW rows are this wave's own -> no barrier needed
    bhalf8 aw0 = *(const bhalf8*)&lW[w * 16 + lr][kg * 8];
    bhalf8 aw1 = *(const bhalf8*)&lW[w * 16 + lr][32 + kg * 8];
#pragma unroll
    for (int n = 0; n < 4; ++n) {
      const unsigned short* vp = vtb + (size_t)(n * 16 + lr) * LL + kt * 64 + kg * 8;
      bhalf8 bv0 = *(const bhalf8*)vp;
      bhalf8 bv1 = *(const bhalf8*)(vp + 32);
      oacc[n] = __builtin_amdgcn_mfma_f32_16x16x32_bf16(aw0, bv0, oacc[n], 0, 0, 0);
      oacc[n] = __builtin_amdgcn_mfma_f32_16x16x32_bf16(aw1, bv1, oacc[n], 0, 0, 0);
    }
    cur ^= 1;
  }
  const int b = bh >> 4, h = bh & 15;
#pragma unroll
  for (int n = 0; n < 4; ++n)
#pragma unroll
    for (int r = 0; r < 4; ++r)
      attn_bf[(size_t)(b * LL + myrow[r]) * DD + h * DH + n * 16 + lr] = f2bf(oacc[n][r]);
}

// ---------- launch ----------
extern "C" void kernel_launch(void* const* d_in, const int* in_sizes, int n_in,
                              void* d_out, int out_size, void* d_ws, size_t ws_size,
                              hipStream_t stream) {
  const float* query = (const float*)d_in[0];
  const float* key   = (const float*)d_in[1];
  const float* value = (const float*)d_in[2];
  // d_in[3] = mask (tril, implemented analytically)
  const float* Wq = (const float*)d_in[4];
  const float* bq = (const float*)d_in[5];
  const float* Wo = (const float*)d_in[6];
  const float* bo = (const float*)d_in[7];
  const float* rel = (const float*)d_in[8];

  if (ws_size < WS_NEED) return;

  char* ws = (char*)d_ws;
  unsigned short* Xbf    = (unsigned short*)(ws + OFF_XBF);
  unsigned short* Wqbf   = (unsigned short*)(ws + OFF_WQBF);
  unsigned short* Wobf   = (unsigned short*)(ws + OFF_WOBF);
  unsigned short* q_bf   = (unsigned short*)(ws + OFF_QBF);
  unsigned short* k_bf   = (unsigned short*)(ws + OFF_KBF);
  unsigned short* vt_bf  = (unsigned short*)(ws + OFF_VTBF);
  unsigned short* attnbf = (unsigned short*)(ws + OFF_ATTNBF);
  float* wAS   = (float*)(ws + OFF_WAS);
  float* bAS   = (float*)(ws + OFF_BAS);
  float* A_arr = (float*)(ws + OFF_AARR);
  float* S_arr = (float*)(ws + OFF_SARR);
  float* M_arr = (float*)(ws + OFF_MARR);
  float* Z_arr = (float*)(ws + OFF_ZARR);

  float* out0 = (float*)d_out;
  float* w_out = out0 + (size_t)MOUT * DD;   // weights region

  cast_f32_bf16<<<4096, 256, 0, stream>>>(query, Xbf, 1048576);
  cast_f32_bf16<<<4096, 256, 0, stream>>>(key,   Xbf + (size_t)MOUT * DD, 1048576);
  cast_f32_bf16<<<4096, 256, 0, stream>>>(value, Xbf + (size_t)2 * MOUT * DD, 1048576);
  cast_f32_bf16<<<1024, 256, 0, stream>>>(Wq, Wqbf, 262144);
  cast_f32_bf16<<<1024, 256, 0, stream>>>(Wo, Wobf, 262144);

  prep_rel<<<128, 256, 0, stream>>>(Wq, bq, rel, wAS, bAS);
  rel_AS<<<512, 256, 0, stream>>>(query, wAS, bAS, A_arr, S_arr);

  gemm_bt<0><<<dim3(96, 8), 256, 0, stream>>>(Xbf, Wqbf, bq, q_bf, k_bf, vt_bf, nullptr);

  attn_a<<<1024, 256, 0, stream>>>(q_bf, k_bf, A_arr, S_arr, M_arr, Z_arr);
  attn_b<<<1024, 256, 0, stream>>>(q_bf, k_bf, vt_bf, A_arr, S_arr, M_arr, Z_arr,
                                   w_out, attnbf);

  gemm_bt<1><<<dim3(32, 8), 256, 0, stream>>>(attnbf, Wobf, bo, nullptr, nullptr, nullptr, out0);
}